// Round 12
// baseline (531.881 us; speedup 1.0000x reference)
//
#include <hip/hip_runtime.h>

#define BB 2
#define DD 1024
#define CC 256
#define TT 32
#define HH 8
#define FF 32
#define EE 1024
#define SCALE 0.17677669529663687f

typedef unsigned short u16;
typedef unsigned int u32;
typedef __attribute__((ext_vector_type(8))) short s8v;    // 8 bf16 (4 VGPRs)
typedef __attribute__((ext_vector_type(4))) float f32x4;

static __device__ __forceinline__ float u2f(u16 u) {
  return __uint_as_float(((u32)u) << 16);
}
static __device__ __forceinline__ u16 f2u(float f) {
  u32 x = __float_as_uint(f);
  x += 0x7fffu + ((x >> 16) & 1u);   // round-to-nearest-even
  return (u16)(x >> 16);
}
// acc += a.lo*b.lo + a.hi*b.hi  (bf16 pairs, f32 accumulate)
static __device__ __forceinline__ float dot2bf(u32 a, u32 b, float c) {
  float d;
  asm("v_dot2_f32_bf16 %0, %1, %2, %3" : "=v"(d) : "v"(a), "v"(b), "v"(c));
  return d;
}
#define D2(acc, a, b) acc = dot2bf(a, b, acc)

// logits for one (t,s,d): q.(k+rk) + k.rqs ; kr = LDS k-row, R regs preloaded,
// q in regs (cached once per thread)
static __device__ __forceinline__ float logits_r(
    const u16* kr,
    uint4 r0, uint4 r1, uint4 r2, uint4 r3,
    uint4 r4, uint4 r5, uint4 r6, uint4 r7,
    uint4 q0, uint4 q1, uint4 q2, uint4 q3) {
  uint4 k0 = *(const uint4*)(kr + 0);
  uint4 k1 = *(const uint4*)(kr + 8);
  uint4 k2 = *(const uint4*)(kr + 16);
  uint4 k3 = *(const uint4*)(kr + 24);
  float xq = 0.f, xr = 0.f, xk = 0.f;
  D2(xq, q0.x, k0.x); D2(xq, q0.y, k0.y); D2(xq, q0.z, k0.z); D2(xq, q0.w, k0.w);
  D2(xq, q1.x, k1.x); D2(xq, q1.y, k1.y); D2(xq, q1.z, k1.z); D2(xq, q1.w, k1.w);
  D2(xq, q2.x, k2.x); D2(xq, q2.y, k2.y); D2(xq, q2.z, k2.z); D2(xq, q2.w, k2.w);
  D2(xq, q3.x, k3.x); D2(xq, q3.y, k3.y); D2(xq, q3.z, k3.z); D2(xq, q3.w, k3.w);
  D2(xr, q0.x, r0.x); D2(xr, q0.y, r0.y); D2(xr, q0.z, r0.z); D2(xr, q0.w, r0.w);
  D2(xr, q1.x, r1.x); D2(xr, q1.y, r1.y); D2(xr, q1.z, r1.z); D2(xr, q1.w, r1.w);
  D2(xr, q2.x, r2.x); D2(xr, q2.y, r2.y); D2(xr, q2.z, r2.z); D2(xr, q2.w, r2.w);
  D2(xr, q3.x, r3.x); D2(xr, q3.y, r3.y); D2(xr, q3.z, r3.z); D2(xr, q3.w, r3.w);
  D2(xk, k0.x, r4.x); D2(xk, k0.y, r4.y); D2(xk, k0.z, r4.z); D2(xk, k0.w, r4.w);
  D2(xk, k1.x, r5.x); D2(xk, k1.y, r5.y); D2(xk, k1.z, r5.z); D2(xk, k1.w, r5.w);
  D2(xk, k2.x, r6.x); D2(xk, k2.y, r6.y); D2(xk, k2.z, r6.z); D2(xk, k2.w, r6.w);
  D2(xk, k3.x, r7.x); D2(xk, k3.y, r7.y); D2(xk, k3.z, r7.z); D2(xk, k3.w, r7.w);
  return xq + xr + xk;
}

// PV for one (f,d): sum_s p[s]*(vT[f][s] + Rv[t,f,s]) ; vr = LDS row, p in regs
static __device__ __forceinline__ float pv_r(
    uint4 p0, uint4 p1, uint4 p2, uint4 p3,
    const u16* vr, uint4 r0, uint4 r1, uint4 r2, uint4 r3) {
  uint4 v0 = *(const uint4*)(vr + 0),  v1 = *(const uint4*)(vr + 8);
  uint4 v2 = *(const uint4*)(vr + 16), v3 = *(const uint4*)(vr + 24);
  float o = 0.f;
  D2(o, p0.x, v0.x); D2(o, p0.y, v0.y); D2(o, p0.z, v0.z); D2(o, p0.w, v0.w);
  D2(o, p1.x, v1.x); D2(o, p1.y, v1.y); D2(o, p1.z, v1.z); D2(o, p1.w, v1.w);
  D2(o, p2.x, v2.x); D2(o, p2.y, v2.y); D2(o, p2.z, v2.z); D2(o, p2.w, v2.w);
  D2(o, p3.x, v3.x); D2(o, p3.y, v3.y); D2(o, p3.z, v3.z); D2(o, p3.w, v3.w);
  D2(o, p0.x, r0.x); D2(o, p0.y, r0.y); D2(o, p0.z, r0.z); D2(o, p0.w, r0.w);
  D2(o, p1.x, r1.x); D2(o, p1.y, r1.y); D2(o, p1.z, r1.z); D2(o, p1.w, r1.w);
  D2(o, p2.x, r2.x); D2(o, p2.y, r2.y); D2(o, p2.z, r2.z); D2(o, p2.w, r2.w);
  D2(o, p3.x, r3.x); D2(o, p3.y, r3.y); D2(o, p3.z, r3.z); D2(o, p3.w, r3.w);
  return o;
}

#define LOADROW8(P, v0, v1, v2, v3, v4, v5, v6, v7)                      \
  v0 = *(const uint4*)((P) + 0);  v1 = *(const uint4*)((P) + 8);         \
  v2 = *(const uint4*)((P) + 16); v3 = *(const uint4*)((P) + 24);        \
  v4 = *(const uint4*)((P) + 32); v5 = *(const uint4*)((P) + 40);        \
  v6 = *(const uint4*)((P) + 48); v7 = *(const uint4*)((P) + 56);
#define LOADROW4(P, v0, v1, v2, v3)                                      \
  v0 = *(const uint4*)((P) + 0);  v1 = *(const uint4*)((P) + 8);         \
  v2 = *(const uint4*)((P) + 16); v3 = *(const uint4*)((P) + 24);

// ---------------------------------------------------------------------------
// K0 fused: [0,2048) groupnorm | [2048,2272) weight-pack | [2272,2464) tpe
__global__ __launch_bounds__(256, 4) void k_f0(
    const float* __restrict__ x, const float* __restrict__ nsc,
    const float* __restrict__ nbi, u16* __restrict__ pun,
    const float* __restrict__ qw, const float* __restrict__ pw,
    const float* __restrict__ ow, const float* __restrict__ tw,
    const float* __restrict__ temb, const float* __restrict__ tb,
    const float* __restrict__ dw, const float* __restrict__ db,
    const int* __restrict__ fidx,
    u16* __restrict__ wpk2, u16* __restrict__ ppk, u16* __restrict__ opk,
    u16* __restrict__ E) {
  const int bid = blockIdx.x;
  const int tid = threadIdx.x;
  __shared__ u16 xt[TT][264];          // gn
  __shared__ float st[EE];             // tpe temb slice
  __shared__ float base_s[CC];         // tpe reduced base
  __shared__ int sfi[TT];

  if (bid < 2048) {
    // ================= groupnorm -> xn (upper half of d_out slot)
    int xcd = bid & 7, jj = bid >> 3;
    int b = xcd >> 2;
    int d = (xcd & 3) * 256 + jj;
    const size_t xbase = ((size_t)(b * DD + d)) * 8192;
    u16* xnp = pun + xbase * 2 + 8192;
    {
      const int c0 = tid >> 3, tq = tid & 7;
      for (int c = c0; c < CC; c += 32) {
        float4 v = *(const float4*)(x + xbase + (size_t)c * TT + tq * 4);
        xt[tq * 4 + 0][c] = f2u(v.x);
        xt[tq * 4 + 1][c] = f2u(v.y);
        xt[tq * 4 + 2][c] = f2u(v.z);
        xt[tq * 4 + 3][c] = f2u(v.w);
      }
    }
    __syncthreads();
    {
      const int c = tid;
      float s = 0.f, s2 = 0.f;
      for (int t = 0; t < TT; ++t) { float v = u2f(xt[t][c]); s += v; s2 += v * v; }
      s += __shfl_xor(s, 1); s2 += __shfl_xor(s2, 1);
      s += __shfl_xor(s, 2); s2 += __shfl_xor(s2, 2);
      s += __shfl_xor(s, 4); s2 += __shfl_xor(s2, 4);
      const float mean = s * (1.f / 256.f);
      const float var = s2 * (1.f / 256.f) - mean * mean;
      const float rs = rsqrtf(var + 1e-5f);
      const float scv = nsc[c] * rs;
      const float biv = nbi[c] - mean * scv;
      for (int t = 0; t < TT; ++t) xt[t][c] = f2u(u2f(xt[t][c]) * scv + biv);
    }
    __syncthreads();
#pragma unroll
    for (int it = 0; it < 4; ++it) {
      int u = it * 256 + tid;
      int t = u >> 5, c = (u & 31) * 8;
      *(uint4*)(xnp + (size_t)u * 8) = *(const uint4*)&xt[t][c];
    }
  } else if (bid < 2272) {
    // ================= weight packing (bf16 MFMA fragment order)
    int id = (bid - 2048) * 256 + tid;     // 0..57343
    if (id < 24576) {
      int lane = id & 63, ks = (id >> 6) & 7, tile = id >> 9;
      int hh = tile / 6, r = tile % 6, sec = r >> 1, nt = r & 1;
      int nrow = sec * 256 + hh * 32 + nt * 16 + (lane & 15);
      int k = ks * 32 + (lane >> 4) * 8;
      const float* src = qw + (size_t)nrow * 256 + k;
      u16* dst = wpk2 + (size_t)id * 8;
#pragma unroll
      for (int e = 0; e < 8; ++e) dst[e] = f2u(src[e]);
    } else if (id < 32768) {
      int j = id - 24576;
      int lane = j & 63, ks = (j >> 6) & 7, nt = j >> 9;
      int row = nt * 16 + (lane & 15);
      int k = ks * 32 + (lane >> 4) * 8;
      const float* src = pw + (size_t)row * 256 + k;
      u16* dst = ppk + (size_t)j * 8;
#pragma unroll
      for (int e = 0; e < 8; ++e) dst[e] = f2u(src[e]);
    } else {
      int j = id - 32768;
      int lane = j & 63, ks = (j >> 6) & 7, g = j >> 9;
      int n = g >> 4, ntg = g & 15;
      int row = ntg * 16 + (lane & 15);
      int k = ks * 32 + (lane >> 4) * 8;
      const float* src = ow + ((size_t)n * 256 + row) * 256 + k;
      u16* dst = opk + (size_t)j * 8;
#pragma unroll
      for (int e = 0; e < 8; ++e) dst[e] = f2u(src[e]);
    }
  } else {
    // ================= tpe: temb-proj (coalesced direct tw) + dist/silu -> E
    int bid3 = bid - 2272;            // n*64 + b*32 + t
    int t = bid3 & 31, b = (bid3 >> 5) & 1, n = bid3 >> 6;
    for (int e = tid; e < EE; e += 256)
      st[e] = temb[((size_t)b * TT + t) * EE + e];
    if (tid < TT) sfi[tid] = fidx[b * TT + tid];
    __syncthreads();
    const int g = tid & 7, cl = tid >> 3;   // 8 lanes per channel
#pragma unroll
    for (int pass = 0; pass < 8; ++pass) {
      const int c = pass * 32 + cl;
      const float* wr = tw + ((size_t)n * 256 + c) * 1024 + g * 4;
      float acc = 0.f;
      for (int step = 0; step < 32; ++step) {
        float4 wv = *(const float4*)(wr + step * 32);
        float4 sv = *(const float4*)(st + g * 4 + step * 32);
        acc += sv.x * wv.x + sv.y * wv.y + sv.z * wv.z + sv.w * wv.w;
      }
      acc += __shfl_xor(acc, 1);
      acc += __shfl_xor(acc, 2);
      acc += __shfl_xor(acc, 4);
      if (g == 0) base_s[c] = acc;
    }
    __syncthreads();
    const int c = tid;
    float base = base_s[c] + tb[n * 256 + c] + db[n * 256 + c];
    float dw0 = dw[(n * 256 + c) * 3 + 0];
    float dw1 = dw[(n * 256 + c) * 3 + 1];
    float dw2 = dw[(n * 256 + c) * 3 + 2];
    int ft = sfi[t];
    u16* erow = E + ((size_t)n * 2048 + b * 1024 + t * 32) * 256 + c;
    for (int s = 0; s < TT; ++s) {
      int pd = ft - sfi[s];
      float d0 = log1pf((float)(pd > 0 ? pd : 0));
      float d1 = log1pf((float)(pd < 0 ? -pd : 0));
      float d2 = (pd == 0) ? 1.f : 0.f;
      float e = base + d0 * dw0 + d1 * dw1 + d2 * dw2;
      float se = e / (1.f + expf(-e));
      erow[(size_t)s * 256] = f2u(se);
    }
  }
}

// ---------------------------------------------------------------------------
// K2: R = E @ ow^T + ob via MFMA, stored head-major:
//  n=0 (Rq, pre-scaled by SCALE, (t,s)-swapped) -> RKQ[bh][t*32+s][32+f]
//  n=1 (Rk)                                     -> RKQ[bh][t*32+s][f]
//  n=2 (Rv)                                     -> Rv [bh][t][f][s]
__global__ __launch_bounds__(256) void k_rgemm(
    const u16* __restrict__ E, const u16* __restrict__ opk,
    const float* __restrict__ ob,
    u16* __restrict__ RKQ, u16* __restrict__ Rv) {
  int bid = blockIdx.x;                 // 192 = 3n * 32 mblk * 2 nblk
  int n = bid >> 6, rem = bid & 63;
  int mblk = rem >> 1, nblk = rem & 1;
  int tid = threadIdx.x;
  int w = tid >> 6, lane = tid & 63;
  int l15 = lane & 15, l4 = lane >> 4;
  size_t rowbase = (size_t)n * 2048 + mblk * 64;

  f32x4 acc[2][4];
#pragma unroll
  for (int i = 0; i < 2; ++i) {
    int ntg = nblk * 8 + w * 2 + i;
    float ov = ob[n * 256 + ntg * 16 + l15];
#pragma unroll
    for (int mt = 0; mt < 4; ++mt) acc[i][mt] = (f32x4){ov, ov, ov, ov};
  }
  for (int ks = 0; ks < 8; ++ks) {
    s8v a[4];
#pragma unroll
    for (int mt = 0; mt < 4; ++mt)
      a[mt] = *(const s8v*)(E + (rowbase + mt * 16 + l15) * 256 + ks * 32 + l4 * 8);
#pragma unroll
    for (int i = 0; i < 2; ++i) {
      int ntg = nblk * 8 + w * 2 + i;
      s8v bf = *(const s8v*)(opk + (((size_t)(n * 16 + ntg) * 8 + ks) * 64 + lane) * 8);
#pragma unroll
      for (int mt = 0; mt < 4; ++mt)
        acc[i][mt] = __builtin_amdgcn_mfma_f32_16x16x32_bf16(a[mt], bf, acc[i][mt], 0, 0, 0);
    }
  }
#pragma unroll
  for (int i = 0; i < 2; ++i) {
    int cc = (nblk * 8 + w * 2 + i) * 16 + l15;
    int hh = cc >> 5, f = cc & 31;
#pragma unroll
    for (int mt = 0; mt < 4; ++mt)
#pragma unroll
      for (int r = 0; r < 4; ++r) {
        int rloc = mblk * 64 + mt * 16 + l4 * 4 + r;  // 0..2047
        int bb2 = rloc >> 10, tt = (rloc >> 5) & 31, ss = rloc & 31;
        size_t bh = (size_t)(bb2 * 8 + hh);
        float v = acc[i][mt][r];
        if (n == 0)      RKQ[(bh * 1024 + ss * 32 + tt) * 64 + 32 + f] = f2u(v * SCALE);
        else if (n == 1) RKQ[(bh * 1024 + tt * 32 + ss) * 64 + f] = f2u(v);
        else             Rv[((bh * 32 + tt) * 32 + f) * 32 + ss] = f2u(v);
      }
  }
}

// ---------------------------------------------------------------------------
// K4: block = (b, h, 4 consecutive d). R rows in registers across 4 d's.
// NO LDS staging of xn: MFMA A-fragments read directly from global (L1/L2-hot
// via the h-sibling XCD swizzle). LDS = qs/ks/vT only (30.7 KB -> 5 blocks/CU);
// ONE barrier per block; ats overlays qs (dead after q-cache; same-8-lane-group
// read->write, program-ordered).
__global__ __launch_bounds__(256, 5) void k_attn(
    u16* __restrict__ pun, const u16* __restrict__ wpk2,
    const float* __restrict__ qkb,
    const u16* __restrict__ RKQ, const u16* __restrict__ Rv) {
  int bid = blockIdx.x;               // 4096
  int xcd = bid & 7, i5 = bid >> 3;   // i5 0..511
  int b = xcd >> 2;
  int h = i5 & 7;                     // h fastest within XCD
  int dg = (xcd & 3) * 64 + (i5 >> 3);
  int d0 = dg * 4;
  const int tid = threadIdx.x;
  __shared__ u16 qs[4][32][40];        // overlaid by ats after q-cache
  __shared__ u16 ks_[4][32][40];
  __shared__ u16 vT[4][32][40];        // [f][s]
#define ATSP(d, t)  (&qs[d][t][0])

  const int w = tid >> 6, lane = tid & 63;
  const int l15 = lane & 15, l4 = lane >> 4;
  const int t = tid >> 3, j = tid & 7;
  const size_t bh = (size_t)(b * 8 + h);
  const u16* rp0 = RKQ + (bh * 1024 + (size_t)t * 32 + j) * 64;   // +8m*64 rows
  const u16* rv0 = Rv + ((bh * 32 + (size_t)t) * 32 + j) * 32;    // +8i*32 rows

  u16* slot0 = pun + ((size_t)(b * DD + d0)) * 16384;   // O half; +8192 = xn half

  // ==== Phase A: per d, qkv head-slice MFMA (A-frags from global xn)
  for (int d = 0; d < 4; ++d) {
    const u16* xg = slot0 + (size_t)d * 16384 + 8192;
#pragma unroll
    for (int i = 0; i < 3; ++i) {
      const int u = w * 3 + i;          // 0..11
      const int sec = u >> 2;           // 0=q 1=k 2=v
      const int nt = (u >> 1) & 1;
      const int mh = u & 1;
      f32x4 acc = {0.f, 0.f, 0.f, 0.f};
      const u16* wb = wpk2 + ((size_t)((h * 6 + sec * 2 + nt) * 8) * 64 + lane) * 8;
      const u16* ag = xg + (size_t)(mh * 16 + l15) * 256 + l4 * 8;
#pragma unroll
      for (int ks = 0; ks < 8; ++ks) {
        s8v a = *(const s8v*)(ag + ks * 32);
        s8v bf = *(const s8v*)(wb + (size_t)ks * 512);
        acc = __builtin_amdgcn_mfma_f32_16x16x32_bf16(a, bf, acc, 0, 0, 0);
      }
      const int f = nt * 16 + l15;
      const float bias = qkb[sec * 256 + h * 32 + f];
#pragma unroll
      for (int r = 0; r < 4; ++r) {
        const int tt = mh * 16 + l4 * 4 + r;
        const float val = acc[r] + bias;
        if (sec == 0)      qs[d][tt][f] = f2u(val * SCALE);
        else if (sec == 1) ks_[d][tt][f] = f2u(val);
        else               vT[d][f][tt] = f2u(val);
      }
    }
  }
  __syncthreads();   // single barrier: qs/ks/vT all visible

  // ==== Phase B: logits. R rows loaded at consume points, reused for 4 d's.
  uint4 q[4][4];
#pragma unroll
  for (int d = 0; d < 4; ++d) {
    q[d][0] = *(const uint4*)&qs[d][t][0];
    q[d][1] = *(const uint4*)&qs[d][t][8];
    q[d][2] = *(const uint4*)&qs[d][t][16];
    q[d][3] = *(const uint4*)&qs[d][t][24];
  }
  float a[4][4];
  uint4 A0, A1, A2, A3, A4, A5, A6, A7;
  uint4 B0, B1, B2, B3, B4, B5, B6, B7;
  LOADROW8(rp0,          A0, A1, A2, A3, A4, A5, A6, A7)   // m=0
  LOADROW8(rp0 + 8 * 64, B0, B1, B2, B3, B4, B5, B6, B7)   // m=1
#pragma unroll
  for (int d = 0; d < 4; ++d)
    a[d][0] = logits_r(&ks_[d][j][0], A0, A1, A2, A3, A4, A5, A6, A7,
                       q[d][0], q[d][1], q[d][2], q[d][3]);
  LOADROW8(rp0 + 16 * 64, A0, A1, A2, A3, A4, A5, A6, A7)  // m=2
#pragma unroll
  for (int d = 0; d < 4; ++d)
    a[d][1] = logits_r(&ks_[d][j + 8][0], B0, B1, B2, B3, B4, B5, B6, B7,
                       q[d][0], q[d][1], q[d][2], q[d][3]);
  LOADROW8(rp0 + 24 * 64, B0, B1, B2, B3, B4, B5, B6, B7)  // m=3
#pragma unroll
  for (int d = 0; d < 4; ++d)
    a[d][2] = logits_r(&ks_[d][j + 16][0], A0, A1, A2, A3, A4, A5, A6, A7,
                       q[d][0], q[d][1], q[d][2], q[d][3]);
#pragma unroll
  for (int d = 0; d < 4; ++d)
    a[d][3] = logits_r(&ks_[d][j + 24][0], B0, B1, B2, B3, B4, B5, B6, B7,
                       q[d][0], q[d][1], q[d][2], q[d][3]);

  // ==== softmax per d (8-lane groups; same group writes & reads ats row)
#pragma unroll
  for (int d = 0; d < 4; ++d) {
    float mx = fmaxf(fmaxf(a[d][0], a[d][1]), fmaxf(a[d][2], a[d][3]));
    mx = fmaxf(mx, __shfl_xor(mx, 1));
    mx = fmaxf(mx, __shfl_xor(mx, 2));
    mx = fmaxf(mx, __shfl_xor(mx, 4));
    float e0 = __expf(a[d][0] - mx), e1 = __expf(a[d][1] - mx);
    float e2 = __expf(a[d][2] - mx), e3 = __expf(a[d][3] - mx);
    float sum = e0 + e1 + e2 + e3;
    sum += __shfl_xor(sum, 1);
    sum += __shfl_xor(sum, 2);
    sum += __shfl_xor(sum, 4);
    const float inv = 1.f / sum;
    u16* ap = ATSP(d, t);
    ap[j]      = f2u(e0 * inv);
    ap[j + 8]  = f2u(e1 * inv);
    ap[j + 16] = f2u(e2 * inv);
    ap[j + 24] = f2u(e3 * inv);
  }

  // ==== Phase C: PV. Rv rows loaded at consume points, reused for 4 d's.
  uint4 p[4][4];
#pragma unroll
  for (int d = 0; d < 4; ++d) {
    const u16* ap = ATSP(d, t);
    p[d][0] = *(const uint4*)(ap + 0);
    p[d][1] = *(const uint4*)(ap + 8);
    p[d][2] = *(const uint4*)(ap + 16);
    p[d][3] = *(const uint4*)(ap + 24);
  }
  float o[4][4];
  uint4 VA0, VA1, VA2, VA3, VB0, VB1, VB2, VB3;
  LOADROW4(rv0,          VA0, VA1, VA2, VA3)   // f = j
  LOADROW4(rv0 + 8 * 32, VB0, VB1, VB2, VB3)   // f = j+8
#pragma unroll
  for (int d = 0; d < 4; ++d)
    o[d][0] = pv_r(p[d][0], p[d][1], p[d][2], p[d][3], &vT[d][j][0],
                   VA0, VA1, VA2, VA3);
  LOADROW4(rv0 + 16 * 32, VA0, VA1, VA2, VA3)  // f = j+16
#pragma unroll
  for (int d = 0; d < 4; ++d)
    o[d][1] = pv_r(p[d][0], p[d][1], p[d][2], p[d][3], &vT[d][j + 8][0],
                   VB0, VB1, VB2, VB3);
  LOADROW4(rv0 + 24 * 32, VB0, VB1, VB2, VB3)  // f = j+24
#pragma unroll
  for (int d = 0; d < 4; ++d)
    o[d][2] = pv_r(p[d][0], p[d][1], p[d][2], p[d][3], &vT[d][j + 16][0],
                   VA0, VA1, VA2, VA3);
#pragma unroll
  for (int d = 0; d < 4; ++d)
    o[d][3] = pv_r(p[d][0], p[d][1], p[d][2], p[d][3], &vT[d][j + 24][0],
                   VB0, VB1, VB2, VB3);

#pragma unroll
  for (int d = 0; d < 4; ++d) {
    u16* op = slot0 + (size_t)d * 16384 + (size_t)t * 256 + h * 32 + j;
    op[0]  = f2u(o[d][0]);
    op[8]  = f2u(o[d][1]);
    op[16] = f2u(o[d][2]);
    op[24] = f2u(o[d][3]);
  }
#undef ATSP
}

// ---------------------------------------------------------------------------
// K5: per (b,d): proj MFMA + bias + residual(xn) -> out [b][d][c][t] f32
__global__ __launch_bounds__(256, 4) void k_proj(
    u16* __restrict__ pun, const u16* __restrict__ ppk,
    const float* __restrict__ pb, float* __restrict__ out) {
  int bid = blockIdx.x;
  int xcd = bid & 7, jj = bid >> 3;
  int b = xcd >> 2;
  int d = (xcd & 3) * 256 + jj;
  const int tid = threadIdx.x;
  __shared__ u16 obuf[32][264];
  __shared__ u16 xs[32][264];
  const size_t nbase = ((size_t)(b * DD + d)) * 8192;
  u16* slot = pun + nbase * 2;
#pragma unroll
  for (int it = 0; it < 4; ++it) {
    int u = it * 256 + tid;
    int t = u >> 5, c = (u & 31) * 8;
    *(uint4*)&obuf[t][c] = *(const uint4*)(slot + (size_t)u * 8);
    *(uint4*)&xs[t][c]   = *(const uint4*)(slot + 8192 + (size_t)u * 8);
  }
  __syncthreads();

  const int w = tid >> 6, lane = tid & 63;
  const int l15 = lane & 15, l4 = lane >> 4;
  f32x4 pacc[4][2];
#pragma unroll
  for (int i = 0; i < 4; ++i) {
    pacc[i][0] = (f32x4){0.f, 0.f, 0.f, 0.f};
    pacc[i][1] = (f32x4){0.f, 0.f, 0.f, 0.f};
  }
  for (int ks = 0; ks < 8; ++ks) {
    s8v a0 = *(const s8v*)&obuf[l15][ks * 32 + l4 * 8];
    s8v a1 = *(const s8v*)&obuf[16 + l15][ks * 32 + l4 * 8];
#pragma unroll
    for (int i = 0; i < 4; ++i) {
      s8v bf = *(const s8v*)(ppk + ((size_t)((w * 4 + i) * 8 + ks) * 64 + lane) * 8);
      pacc[i][0] = __builtin_amdgcn_mfma_f32_16x16x32_bf16(a0, bf, pacc[i][0], 0, 0, 0);
      pacc[i][1] = __builtin_amdgcn_mfma_f32_16x16x32_bf16(a1, bf, pacc[i][1], 0, 0, 0);
    }
  }
#pragma unroll
  for (int i = 0; i < 4; ++i) {
    const int co = (w * 4 + i) * 16 + l15;
    const float pbv = pb[co];
#pragma unroll
    for (int mt = 0; mt < 2; ++mt) {
      const int t0 = mt * 16 + l4 * 4;
      float4 sv;
      sv.x = pacc[i][mt][0] + u2f(xs[t0 + 0][co]) + pbv;
      sv.y = pacc[i][mt][1] + u2f(xs[t0 + 1][co]) + pbv;
      sv.z = pacc[i][mt][2] + u2f(xs[t0 + 2][co]) + pbv;
      sv.w = pacc[i][mt][3] + u2f(xs[t0 + 3][co]) + pbv;
      *(float4*)(out + nbase + (size_t)co * TT + t0) = sv;
    }
  }
}

// ---------------------------------------------------------------------------
extern "C" void kernel_launch(void* const* d_in, const int* in_sizes, int n_in,
                              void* d_out, int out_size, void* d_ws, size_t ws_size,
                              hipStream_t stream) {
  const float* x      = (const float*)d_in[0];
  const float* temb   = (const float*)d_in[1];
  const float* nsc    = (const float*)d_in[2];
  const float* nbi    = (const float*)d_in[3];
  const float* qkv_w  = (const float*)d_in[4];
  const float* qkv_b  = (const float*)d_in[5];
  const float* proj_w = (const float*)d_in[6];
  const float* proj_b = (const float*)d_in[7];
  const float* dw     = (const float*)d_in[8];
  const float* db     = (const float*)d_in[9];
  const float* tw     = (const float*)d_in[10];
  const float* tb     = (const float*)d_in[11];
  const float* ow     = (const float*)d_in[12];
  const float* ob     = (const float*)d_in[13];
  const int*   fidx   = (const int*)d_in[14];
  float* out = (float*)d_out;
  u16* pun = (u16*)d_out;                        // slot-packed O (lo) + xn (hi)

  u16* wpk2 = (u16*)d_ws;                        // 196608 u16
  u16* ppk  = wpk2 + 196608;                     // 65536
  u16* opk  = ppk + 65536;                       // 196608
  u16* E    = opk + 196608;                      // 1572864
  u16* RKQ  = E + 1572864;                       // 1048576
  u16* Rv   = RKQ + 1048576;                     // 524288   (~7.2 MB total)

  k_f0<<<2464, 256, 0, stream>>>(x, nsc, nbi, pun, qkv_w, proj_w, ow, tw,
                                 temb, tb, dw, db, fidx, wpk2, ppk, opk, E);
  k_rgemm<<<192, 256, 0, stream>>>(E, opk, ob, RKQ, Rv);
  k_attn<<<4096, 256, 0, stream>>>(pun, wpk2, qkv_b, RKQ, Rv);
  k_proj<<<2048, 256, 0, stream>>>(pun, ppk, proj_b, out);
}

// Round 13
// 217.891 us; speedup vs baseline: 2.4410x; 2.4410x over previous
//
#include <hip/hip_runtime.h>

#define BB 2
#define DD 1024
#define CC 256
#define TT 32
#define HH 8
#define FF 32
#define EE 1024
#define SCALE 0.17677669529663687f

typedef unsigned short u16;
typedef unsigned int u32;
typedef __attribute__((ext_vector_type(8))) short s8v;    // 8 bf16 (4 VGPRs)
typedef __attribute__((ext_vector_type(4))) float f32x4;

static __device__ __forceinline__ float u2f(u16 u) {
  return __uint_as_float(((u32)u) << 16);
}
static __device__ __forceinline__ u16 f2u(float f) {
  u32 x = __float_as_uint(f);
  x += 0x7fffu + ((x >> 16) & 1u);   // round-to-nearest-even
  return (u16)(x >> 16);
}
// acc += a.lo*b.lo + a.hi*b.hi  (bf16 pairs, f32 accumulate)
static __device__ __forceinline__ float dot2bf(u32 a, u32 b, float c) {
  float d;
  asm("v_dot2_f32_bf16 %0, %1, %2, %3" : "=v"(d) : "v"(a), "v"(b), "v"(c));
  return d;
}
#define D2(acc, a, b) acc = dot2bf(a, b, acc)

// logits for one (t,s,d): q.(k+rk) + k.rqs ; kr = LDS k-row, R regs preloaded,
// q in regs (cached once per thread)
static __device__ __forceinline__ float logits_r(
    const u16* kr,
    uint4 r0, uint4 r1, uint4 r2, uint4 r3,
    uint4 r4, uint4 r5, uint4 r6, uint4 r7,
    uint4 q0, uint4 q1, uint4 q2, uint4 q3) {
  uint4 k0 = *(const uint4*)(kr + 0);
  uint4 k1 = *(const uint4*)(kr + 8);
  uint4 k2 = *(const uint4*)(kr + 16);
  uint4 k3 = *(const uint4*)(kr + 24);
  float xq = 0.f, xr = 0.f, xk = 0.f;
  D2(xq, q0.x, k0.x); D2(xq, q0.y, k0.y); D2(xq, q0.z, k0.z); D2(xq, q0.w, k0.w);
  D2(xq, q1.x, k1.x); D2(xq, q1.y, k1.y); D2(xq, q1.z, k1.z); D2(xq, q1.w, k1.w);
  D2(xq, q2.x, k2.x); D2(xq, q2.y, k2.y); D2(xq, q2.z, k2.z); D2(xq, q2.w, k2.w);
  D2(xq, q3.x, k3.x); D2(xq, q3.y, k3.y); D2(xq, q3.z, k3.z); D2(xq, q3.w, k3.w);
  D2(xr, q0.x, r0.x); D2(xr, q0.y, r0.y); D2(xr, q0.z, r0.z); D2(xr, q0.w, r0.w);
  D2(xr, q1.x, r1.x); D2(xr, q1.y, r1.y); D2(xr, q1.z, r1.z); D2(xr, q1.w, r1.w);
  D2(xr, q2.x, r2.x); D2(xr, q2.y, r2.y); D2(xr, q2.z, r2.z); D2(xr, q2.w, r2.w);
  D2(xr, q3.x, r3.x); D2(xr, q3.y, r3.y); D2(xr, q3.z, r3.z); D2(xr, q3.w, r3.w);
  D2(xk, k0.x, r4.x); D2(xk, k0.y, r4.y); D2(xk, k0.z, r4.z); D2(xk, k0.w, r4.w);
  D2(xk, k1.x, r5.x); D2(xk, k1.y, r5.y); D2(xk, k1.z, r5.z); D2(xk, k1.w, r5.w);
  D2(xk, k2.x, r6.x); D2(xk, k2.y, r6.y); D2(xk, k2.z, r6.z); D2(xk, k2.w, r6.w);
  D2(xk, k3.x, r7.x); D2(xk, k3.y, r7.y); D2(xk, k3.z, r7.z); D2(xk, k3.w, r7.w);
  return xq + xr + xk;
}

// PV for one (f,d): sum_s p[s]*(vT[f][s] + Rv[t,f,s]) ; vr = LDS row, p in regs
static __device__ __forceinline__ float pv_r(
    uint4 p0, uint4 p1, uint4 p2, uint4 p3,
    const u16* vr, uint4 r0, uint4 r1, uint4 r2, uint4 r3) {
  uint4 v0 = *(const uint4*)(vr + 0),  v1 = *(const uint4*)(vr + 8);
  uint4 v2 = *(const uint4*)(vr + 16), v3 = *(const uint4*)(vr + 24);
  float o = 0.f;
  D2(o, p0.x, v0.x); D2(o, p0.y, v0.y); D2(o, p0.z, v0.z); D2(o, p0.w, v0.w);
  D2(o, p1.x, v1.x); D2(o, p1.y, v1.y); D2(o, p1.z, v1.z); D2(o, p1.w, v1.w);
  D2(o, p2.x, v2.x); D2(o, p2.y, v2.y); D2(o, p2.z, v2.z); D2(o, p2.w, v2.w);
  D2(o, p3.x, v3.x); D2(o, p3.y, v3.y); D2(o, p3.z, v3.z); D2(o, p3.w, v3.w);
  D2(o, p0.x, r0.x); D2(o, p0.y, r0.y); D2(o, p0.z, r0.z); D2(o, p0.w, r0.w);
  D2(o, p1.x, r1.x); D2(o, p1.y, r1.y); D2(o, p1.z, r1.z); D2(o, p1.w, r1.w);
  D2(o, p2.x, r2.x); D2(o, p2.y, r2.y); D2(o, p2.z, r2.z); D2(o, p2.w, r2.w);
  D2(o, p3.x, r3.x); D2(o, p3.y, r3.y); D2(o, p3.z, r3.z); D2(o, p3.w, r3.w);
  return o;
}

#define LOADROW8(P, v0, v1, v2, v3, v4, v5, v6, v7)                      \
  v0 = *(const uint4*)((P) + 0);  v1 = *(const uint4*)((P) + 8);         \
  v2 = *(const uint4*)((P) + 16); v3 = *(const uint4*)((P) + 24);        \
  v4 = *(const uint4*)((P) + 32); v5 = *(const uint4*)((P) + 40);        \
  v6 = *(const uint4*)((P) + 48); v7 = *(const uint4*)((P) + 56);
#define LOADROW4(P, v0, v1, v2, v3)                                      \
  v0 = *(const uint4*)((P) + 0);  v1 = *(const uint4*)((P) + 8);         \
  v2 = *(const uint4*)((P) + 16); v3 = *(const uint4*)((P) + 24);

// ---------------------------------------------------------------------------
// K0 fused: [0,2048) groupnorm | [2048,2272) weight-pack | [2272,2464) tpe
__global__ __launch_bounds__(256, 4) void k_f0(
    const float* __restrict__ x, const float* __restrict__ nsc,
    const float* __restrict__ nbi, u16* __restrict__ pun,
    const float* __restrict__ qw, const float* __restrict__ pw,
    const float* __restrict__ ow, const float* __restrict__ tw,
    const float* __restrict__ temb, const float* __restrict__ tb,
    const float* __restrict__ dw, const float* __restrict__ db,
    const int* __restrict__ fidx,
    u16* __restrict__ wpk2, u16* __restrict__ ppk, u16* __restrict__ opk,
    u16* __restrict__ E) {
  const int bid = blockIdx.x;
  const int tid = threadIdx.x;
  __shared__ u16 xt[TT][264];          // gn
  __shared__ float st[EE];             // tpe temb slice
  __shared__ float base_s[CC];         // tpe reduced base
  __shared__ int sfi[TT];

  if (bid < 2048) {
    // ================= groupnorm -> xn (upper half of d_out slot)
    int xcd = bid & 7, jj = bid >> 3;
    int b = xcd >> 2;
    int d = (xcd & 3) * 256 + jj;
    const size_t xbase = ((size_t)(b * DD + d)) * 8192;
    u16* xnp = pun + xbase * 2 + 8192;
    {
      const int c0 = tid >> 3, tq = tid & 7;
      for (int c = c0; c < CC; c += 32) {
        float4 v = *(const float4*)(x + xbase + (size_t)c * TT + tq * 4);
        xt[tq * 4 + 0][c] = f2u(v.x);
        xt[tq * 4 + 1][c] = f2u(v.y);
        xt[tq * 4 + 2][c] = f2u(v.z);
        xt[tq * 4 + 3][c] = f2u(v.w);
      }
    }
    __syncthreads();
    {
      const int c = tid;
      float s = 0.f, s2 = 0.f;
      for (int t = 0; t < TT; ++t) { float v = u2f(xt[t][c]); s += v; s2 += v * v; }
      s += __shfl_xor(s, 1); s2 += __shfl_xor(s2, 1);
      s += __shfl_xor(s, 2); s2 += __shfl_xor(s2, 2);
      s += __shfl_xor(s, 4); s2 += __shfl_xor(s2, 4);
      const float mean = s * (1.f / 256.f);
      const float var = s2 * (1.f / 256.f) - mean * mean;
      const float rs = rsqrtf(var + 1e-5f);
      const float scv = nsc[c] * rs;
      const float biv = nbi[c] - mean * scv;
      for (int t = 0; t < TT; ++t) xt[t][c] = f2u(u2f(xt[t][c]) * scv + biv);
    }
    __syncthreads();
#pragma unroll
    for (int it = 0; it < 4; ++it) {
      int u = it * 256 + tid;
      int t = u >> 5, c = (u & 31) * 8;
      *(uint4*)(xnp + (size_t)u * 8) = *(const uint4*)&xt[t][c];
    }
  } else if (bid < 2272) {
    // ================= weight packing (bf16 MFMA fragment order)
    int id = (bid - 2048) * 256 + tid;     // 0..57343
    if (id < 24576) {
      int lane = id & 63, ks = (id >> 6) & 7, tile = id >> 9;
      int hh = tile / 6, r = tile % 6, sec = r >> 1, nt = r & 1;
      int nrow = sec * 256 + hh * 32 + nt * 16 + (lane & 15);
      int k = ks * 32 + (lane >> 4) * 8;
      const float* src = qw + (size_t)nrow * 256 + k;
      u16* dst = wpk2 + (size_t)id * 8;
#pragma unroll
      for (int e = 0; e < 8; ++e) dst[e] = f2u(src[e]);
    } else if (id < 32768) {
      int j = id - 24576;
      int lane = j & 63, ks = (j >> 6) & 7, nt = j >> 9;
      int row = nt * 16 + (lane & 15);
      int k = ks * 32 + (lane >> 4) * 8;
      const float* src = pw + (size_t)row * 256 + k;
      u16* dst = ppk + (size_t)j * 8;
#pragma unroll
      for (int e = 0; e < 8; ++e) dst[e] = f2u(src[e]);
    } else {
      int j = id - 32768;
      int lane = j & 63, ks = (j >> 6) & 7, g = j >> 9;
      int n = g >> 4, ntg = g & 15;
      int row = ntg * 16 + (lane & 15);
      int k = ks * 32 + (lane >> 4) * 8;
      const float* src = ow + ((size_t)n * 256 + row) * 256 + k;
      u16* dst = opk + (size_t)j * 8;
#pragma unroll
      for (int e = 0; e < 8; ++e) dst[e] = f2u(src[e]);
    }
  } else {
    // ================= tpe: temb-proj (coalesced direct tw) + dist/silu -> E
    int bid3 = bid - 2272;            // n*64 + b*32 + t
    int t = bid3 & 31, b = (bid3 >> 5) & 1, n = bid3 >> 6;
    for (int e = tid; e < EE; e += 256)
      st[e] = temb[((size_t)b * TT + t) * EE + e];
    if (tid < TT) sfi[tid] = fidx[b * TT + tid];
    __syncthreads();
    const int g = tid & 7, cl = tid >> 3;   // 8 lanes per channel
#pragma unroll
    for (int pass = 0; pass < 8; ++pass) {
      const int c = pass * 32 + cl;
      const float* wr = tw + ((size_t)n * 256 + c) * 1024 + g * 4;
      float acc = 0.f;
      for (int step = 0; step < 32; ++step) {
        float4 wv = *(const float4*)(wr + step * 32);
        float4 sv = *(const float4*)(st + g * 4 + step * 32);
        acc += sv.x * wv.x + sv.y * wv.y + sv.z * wv.z + sv.w * wv.w;
      }
      acc += __shfl_xor(acc, 1);
      acc += __shfl_xor(acc, 2);
      acc += __shfl_xor(acc, 4);
      if (g == 0) base_s[c] = acc;
    }
    __syncthreads();
    const int c = tid;
    float base = base_s[c] + tb[n * 256 + c] + db[n * 256 + c];
    float dw0 = dw[(n * 256 + c) * 3 + 0];
    float dw1 = dw[(n * 256 + c) * 3 + 1];
    float dw2 = dw[(n * 256 + c) * 3 + 2];
    int ft = sfi[t];
    u16* erow = E + ((size_t)n * 2048 + b * 1024 + t * 32) * 256 + c;
    for (int s = 0; s < TT; ++s) {
      int pd = ft - sfi[s];
      float d0 = log1pf((float)(pd > 0 ? pd : 0));
      float d1 = log1pf((float)(pd < 0 ? -pd : 0));
      float d2 = (pd == 0) ? 1.f : 0.f;
      float e = base + d0 * dw0 + d1 * dw1 + d2 * dw2;
      float se = e / (1.f + expf(-e));
      erow[(size_t)s * 256] = f2u(se);
    }
  }
}

// ---------------------------------------------------------------------------
// K2: R = E @ ow^T + ob via MFMA, stored head-major:
//  n=0 (Rq, pre-scaled by SCALE, (t,s)-swapped) -> RKQ[bh][t*32+s][32+f]
//  n=1 (Rk)                                     -> RKQ[bh][t*32+s][f]
//  n=2 (Rv)                                     -> Rv [bh][t][f][s]
__global__ __launch_bounds__(256) void k_rgemm(
    const u16* __restrict__ E, const u16* __restrict__ opk,
    const float* __restrict__ ob,
    u16* __restrict__ RKQ, u16* __restrict__ Rv) {
  int bid = blockIdx.x;                 // 192 = 3n * 32 mblk * 2 nblk
  int n = bid >> 6, rem = bid & 63;
  int mblk = rem >> 1, nblk = rem & 1;
  int tid = threadIdx.x;
  int w = tid >> 6, lane = tid & 63;
  int l15 = lane & 15, l4 = lane >> 4;
  size_t rowbase = (size_t)n * 2048 + mblk * 64;

  f32x4 acc[2][4];
#pragma unroll
  for (int i = 0; i < 2; ++i) {
    int ntg = nblk * 8 + w * 2 + i;
    float ov = ob[n * 256 + ntg * 16 + l15];
#pragma unroll
    for (int mt = 0; mt < 4; ++mt) acc[i][mt] = (f32x4){ov, ov, ov, ov};
  }
  for (int ks = 0; ks < 8; ++ks) {
    s8v a[4];
#pragma unroll
    for (int mt = 0; mt < 4; ++mt)
      a[mt] = *(const s8v*)(E + (rowbase + mt * 16 + l15) * 256 + ks * 32 + l4 * 8);
#pragma unroll
    for (int i = 0; i < 2; ++i) {
      int ntg = nblk * 8 + w * 2 + i;
      s8v bf = *(const s8v*)(opk + (((size_t)(n * 16 + ntg) * 8 + ks) * 64 + lane) * 8);
#pragma unroll
      for (int mt = 0; mt < 4; ++mt)
        acc[i][mt] = __builtin_amdgcn_mfma_f32_16x16x32_bf16(a[mt], bf, acc[i][mt], 0, 0, 0);
    }
  }
#pragma unroll
  for (int i = 0; i < 2; ++i) {
    int cc = (nblk * 8 + w * 2 + i) * 16 + l15;
    int hh = cc >> 5, f = cc & 31;
#pragma unroll
    for (int mt = 0; mt < 4; ++mt)
#pragma unroll
      for (int r = 0; r < 4; ++r) {
        int rloc = mblk * 64 + mt * 16 + l4 * 4 + r;  // 0..2047
        int bb2 = rloc >> 10, tt = (rloc >> 5) & 31, ss = rloc & 31;
        size_t bh = (size_t)(bb2 * 8 + hh);
        float v = acc[i][mt][r];
        if (n == 0)      RKQ[(bh * 1024 + ss * 32 + tt) * 64 + 32 + f] = f2u(v * SCALE);
        else if (n == 1) RKQ[(bh * 1024 + tt * 32 + ss) * 64 + f] = f2u(v);
        else             Rv[((bh * 32 + tt) * 32 + f) * 32 + ss] = f2u(v);
      }
  }
}

// ---------------------------------------------------------------------------
// K4: block = (b, h, 4 consecutive d). R rows in registers across 4 d's
// (r9/r11 structure); xsbuf stride 260 (conflict-free A-frag reads); vT
// writes packed (ushort4); m=0 RKQ row issued before the final barrier.
__global__ __launch_bounds__(256, 3) void k_attn(
    u16* __restrict__ pun, const u16* __restrict__ wpk2,
    const float* __restrict__ qkb,
    const u16* __restrict__ RKQ, const u16* __restrict__ Rv) {
  int bid = blockIdx.x;               // 4096
  int xcd = bid & 7, i5 = bid >> 3;   // i5 0..511
  int b = xcd >> 2;
  int h = i5 & 7;                     // h fastest within XCD
  int dg = (xcd & 3) * 64 + (i5 >> 3);
  int d0 = dg * 4;
  const int tid = threadIdx.x;
  __shared__ u16 xsbuf[32 * 260];      // Phase A: xs; Phase B/C: ats overlay
  __shared__ u16 qs[4][32][40];
  __shared__ u16 ks_[4][32][40];
  __shared__ u16 vT[4][32][40];        // [f][s]
#define XS_(r, c)   xsbuf[(r) * 260 + (c)]
#define ATSP(d, t)  (xsbuf + ((d) * 32 + (t)) * 40)

  const int w = tid >> 6, lane = tid & 63;
  const int l15 = lane & 15, l4 = lane >> 4;
  const int t = tid >> 3, j = tid & 7;
  const size_t bh = (size_t)(b * 8 + h);
  const u16* rp0 = RKQ + (bh * 1024 + (size_t)t * 32 + j) * 64;   // +8m*64 rows
  const u16* rv0 = Rv + ((bh * 32 + (size_t)t) * 32 + j) * 32;    // +8i*32 rows

  u16* slot0 = pun + ((size_t)(b * DD + d0)) * 16384;   // O half; +8192 = xn half

  // ---- prologue: xn tile for d=0
  const u16* xp0 = slot0 + 8192;
  uint4 xr0 = *(const uint4*)(xp0 + (size_t)tid * 8);
  uint4 xr1 = *(const uint4*)(xp0 + (size_t)(256 + tid) * 8);
  uint4 xr2 = *(const uint4*)(xp0 + (size_t)(512 + tid) * 8);
  uint4 xr3 = *(const uint4*)(xp0 + (size_t)(768 + tid) * 8);

  uint4 A0, A1, A2, A3, A4, A5, A6, A7;   // m=0 issued pre-barrier (last d)

  // ==== Phase A: per d, stage xs + qkv head-slice MFMA -> qs/ks_/vT[d]
#pragma unroll
  for (int d = 0; d < 4; ++d) {
    *(uint4*)&XS_((tid >> 5), (tid & 31) * 8) = xr0;
    *(uint4*)&XS_(8 + (tid >> 5), (tid & 31) * 8) = xr1;
    *(uint4*)&XS_(16 + (tid >> 5), (tid & 31) * 8) = xr2;
    *(uint4*)&XS_(24 + (tid >> 5), (tid & 31) * 8) = xr3;
    __syncthreads();
    if (d < 3) {   // prefetch next xn tile under MFMA
      const u16* nx = slot0 + (size_t)(d + 1) * 16384 + 8192;
      xr0 = *(const uint4*)(nx + (size_t)tid * 8);
      xr1 = *(const uint4*)(nx + (size_t)(256 + tid) * 8);
      xr2 = *(const uint4*)(nx + (size_t)(512 + tid) * 8);
      xr3 = *(const uint4*)(nx + (size_t)(768 + tid) * 8);
    }
#pragma unroll
    for (int i = 0; i < 3; ++i) {
      const int u = w * 3 + i;          // 0..11
      const int sec = u >> 2;           // 0=q 1=k 2=v
      const int nt = (u >> 1) & 1;
      const int mh = u & 1;
      f32x4 acc = {0.f, 0.f, 0.f, 0.f};
      const u16* wb = wpk2 + ((size_t)((h * 6 + sec * 2 + nt) * 8) * 64 + lane) * 8;
#pragma unroll
      for (int ks = 0; ks < 8; ++ks) {
        s8v a = *(const s8v*)&XS_(mh * 16 + l15, ks * 32 + l4 * 8);
        s8v bf = *(const s8v*)(wb + (size_t)ks * 512);
        acc = __builtin_amdgcn_mfma_f32_16x16x32_bf16(a, bf, acc, 0, 0, 0);
      }
      const int f = nt * 16 + l15;
      const float bias = qkb[sec * 256 + h * 32 + f];
      if (sec == 2) {
        ushort4 pk;
        pk.x = f2u(acc[0] + bias);
        pk.y = f2u(acc[1] + bias);
        pk.z = f2u(acc[2] + bias);
        pk.w = f2u(acc[3] + bias);
        *(ushort4*)&vT[d][f][mh * 16 + l4 * 4] = pk;
      } else {
#pragma unroll
        for (int r = 0; r < 4; ++r) {
          const int tt = mh * 16 + l4 * 4 + r;
          const float val = acc[r] + bias;
          if (sec == 0) qs[d][tt][f] = f2u(val * SCALE);
          else          ks_[d][tt][f] = f2u(val);
        }
      }
    }
    if (d == 3) {   // issue m=0 R rows; latency hides under the barrier wait
      LOADROW8(rp0, A0, A1, A2, A3, A4, A5, A6, A7)
    }
    __syncthreads();   // qs/ks/vT[d] visible; xs reads drained (enables overlay)
  }

  // ==== Phase B: logits. R rows loaded once, reused for 4 d's.
  uint4 q[4][4];
#pragma unroll
  for (int d = 0; d < 4; ++d) {
    q[d][0] = *(const uint4*)&qs[d][t][0];
    q[d][1] = *(const uint4*)&qs[d][t][8];
    q[d][2] = *(const uint4*)&qs[d][t][16];
    q[d][3] = *(const uint4*)&qs[d][t][24];
  }
  float a[4][4];
  uint4 B0, B1, B2, B3, B4, B5, B6, B7;
  LOADROW8(rp0 + 8 * 64, B0, B1, B2, B3, B4, B5, B6, B7)   // m=1
#pragma unroll
  for (int d = 0; d < 4; ++d)
    a[d][0] = logits_r(&ks_[d][j][0], A0, A1, A2, A3, A4, A5, A6, A7,
                       q[d][0], q[d][1], q[d][2], q[d][3]);
  LOADROW8(rp0 + 16 * 64, A0, A1, A2, A3, A4, A5, A6, A7)  // m=2
#pragma unroll
  for (int d = 0; d < 4; ++d)
    a[d][1] = logits_r(&ks_[d][j + 8][0], B0, B1, B2, B3, B4, B5, B6, B7,
                       q[d][0], q[d][1], q[d][2], q[d][3]);
  LOADROW8(rp0 + 24 * 64, B0, B1, B2, B3, B4, B5, B6, B7)  // m=3
#pragma unroll
  for (int d = 0; d < 4; ++d)
    a[d][2] = logits_r(&ks_[d][j + 16][0], A0, A1, A2, A3, A4, A5, A6, A7,
                       q[d][0], q[d][1], q[d][2], q[d][3]);
#pragma unroll
  for (int d = 0; d < 4; ++d)
    a[d][3] = logits_r(&ks_[d][j + 24][0], B0, B1, B2, B3, B4, B5, B6, B7,
                       q[d][0], q[d][1], q[d][2], q[d][3]);

  // ==== softmax per d (8-lane groups; same group writes & reads ats row)
#pragma unroll
  for (int d = 0; d < 4; ++d) {
    float mx = fmaxf(fmaxf(a[d][0], a[d][1]), fmaxf(a[d][2], a[d][3]));
    mx = fmaxf(mx, __shfl_xor(mx, 1));
    mx = fmaxf(mx, __shfl_xor(mx, 2));
    mx = fmaxf(mx, __shfl_xor(mx, 4));
    float e0 = __expf(a[d][0] - mx), e1 = __expf(a[d][1] - mx);
    float e2 = __expf(a[d][2] - mx), e3 = __expf(a[d][3] - mx);
    float sum = e0 + e1 + e2 + e3;
    sum += __shfl_xor(sum, 1);
    sum += __shfl_xor(sum, 2);
    sum += __shfl_xor(sum, 4);
    const float inv = 1.f / sum;
    u16* ap = ATSP(d, t);
    ap[j]      = f2u(e0 * inv);
    ap[j + 8]  = f2u(e1 * inv);
    ap[j + 16] = f2u(e2 * inv);
    ap[j + 24] = f2u(e3 * inv);
  }

  // ==== Phase C: PV. Rv rows loaded once, reused for 4 d's.
  uint4 p[4][4];
#pragma unroll
  for (int d = 0; d < 4; ++d) {
    const u16* ap = ATSP(d, t);
    p[d][0] = *(const uint4*)(ap + 0);
    p[d][1] = *(const uint4*)(ap + 8);
    p[d][2] = *(const uint4*)(ap + 16);
    p[d][3] = *(const uint4*)(ap + 24);
  }
  float o[4][4];
  uint4 VA0, VA1, VA2, VA3, VB0, VB1, VB2, VB3;
  LOADROW4(rv0,          VA0, VA1, VA2, VA3)   // f = j
  LOADROW4(rv0 + 8 * 32, VB0, VB1, VB2, VB3)   // f = j+8
#pragma unroll
  for (int d = 0; d < 4; ++d)
    o[d][0] = pv_r(p[d][0], p[d][1], p[d][2], p[d][3], &vT[d][j][0],
                   VA0, VA1, VA2, VA3);
  LOADROW4(rv0 + 16 * 32, VA0, VA1, VA2, VA3)  // f = j+16
#pragma unroll
  for (int d = 0; d < 4; ++d)
    o[d][1] = pv_r(p[d][0], p[d][1], p[d][2], p[d][3], &vT[d][j + 8][0],
                   VB0, VB1, VB2, VB3);
  LOADROW4(rv0 + 24 * 32, VB0, VB1, VB2, VB3)  // f = j+24
#pragma unroll
  for (int d = 0; d < 4; ++d)
    o[d][2] = pv_r(p[d][0], p[d][1], p[d][2], p[d][3], &vT[d][j + 16][0],
                   VA0, VA1, VA2, VA3);
#pragma unroll
  for (int d = 0; d < 4; ++d)
    o[d][3] = pv_r(p[d][0], p[d][1], p[d][2], p[d][3], &vT[d][j + 24][0],
                   VB0, VB1, VB2, VB3);

#pragma unroll
  for (int d = 0; d < 4; ++d) {
    u16* op = slot0 + (size_t)d * 16384 + (size_t)t * 256 + h * 32 + j;
    op[0]  = f2u(o[d][0]);
    op[8]  = f2u(o[d][1]);
    op[16] = f2u(o[d][2]);
    op[24] = f2u(o[d][3]);
  }
#undef XS_
#undef ATSP
}

// ---------------------------------------------------------------------------
// K5: per (b,d): proj MFMA + bias + residual(xn) -> out [b][d][c][t] f32
__global__ __launch_bounds__(256, 4) void k_proj(
    u16* __restrict__ pun, const u16* __restrict__ ppk,
    const float* __restrict__ pb, float* __restrict__ out) {
  int bid = blockIdx.x;
  int xcd = bid & 7, jj = bid >> 3;
  int b = xcd >> 2;
  int d = (xcd & 3) * 256 + jj;
  const int tid = threadIdx.x;
  __shared__ u16 obuf[32][264];
  __shared__ u16 xs[32][264];
  const size_t nbase = ((size_t)(b * DD + d)) * 8192;
  u16* slot = pun + nbase * 2;
#pragma unroll
  for (int it = 0; it < 4; ++it) {
    int u = it * 256 + tid;
    int t = u >> 5, c = (u & 31) * 8;
    *(uint4*)&obuf[t][c] = *(const uint4*)(slot + (size_t)u * 8);
    *(uint4*)&xs[t][c]   = *(const uint4*)(slot + 8192 + (size_t)u * 8);
  }
  __syncthreads();

  const int w = tid >> 6, lane = tid & 63;
  const int l15 = lane & 15, l4 = lane >> 4;
  f32x4 pacc[4][2];
#pragma unroll
  for (int i = 0; i < 4; ++i) {
    pacc[i][0] = (f32x4){0.f, 0.f, 0.f, 0.f};
    pacc[i][1] = (f32x4){0.f, 0.f, 0.f, 0.f};
  }
  for (int ks = 0; ks < 8; ++ks) {
    s8v a0 = *(const s8v*)&obuf[l15][ks * 32 + l4 * 8];
    s8v a1 = *(const s8v*)&obuf[16 + l15][ks * 32 + l4 * 8];
#pragma unroll
    for (int i = 0; i < 4; ++i) {
      s8v bf = *(const s8v*)(ppk + ((size_t)((w * 4 + i) * 8 + ks) * 64 + lane) * 8);
      pacc[i][0] = __builtin_amdgcn_mfma_f32_16x16x32_bf16(a0, bf, pacc[i][0], 0, 0, 0);
      pacc[i][1] = __builtin_amdgcn_mfma_f32_16x16x32_bf16(a1, bf, pacc[i][1], 0, 0, 0);
    }
  }
#pragma unroll
  for (int i = 0; i < 4; ++i) {
    const int co = (w * 4 + i) * 16 + l15;
    const float pbv = pb[co];
#pragma unroll
    for (int mt = 0; mt < 2; ++mt) {
      const int t0 = mt * 16 + l4 * 4;
      float4 sv;
      sv.x = pacc[i][mt][0] + u2f(xs[t0 + 0][co]) + pbv;
      sv.y = pacc[i][mt][1] + u2f(xs[t0 + 1][co]) + pbv;
      sv.z = pacc[i][mt][2] + u2f(xs[t0 + 2][co]) + pbv;
      sv.w = pacc[i][mt][3] + u2f(xs[t0 + 3][co]) + pbv;
      *(float4*)(out + nbase + (size_t)co * TT + t0) = sv;
    }
  }
}

// ---------------------------------------------------------------------------
extern "C" void kernel_launch(void* const* d_in, const int* in_sizes, int n_in,
                              void* d_out, int out_size, void* d_ws, size_t ws_size,
                              hipStream_t stream) {
  const float* x      = (const float*)d_in[0];
  const float* temb   = (const float*)d_in[1];
  const float* nsc    = (const float*)d_in[2];
  const float* nbi    = (const float*)d_in[3];
  const float* qkv_w  = (const float*)d_in[4];
  const float* qkv_b  = (const float*)d_in[5];
  const float* proj_w = (const float*)d_in[6];
  const float* proj_b = (const float*)d_in[7];
  const float* dw     = (const float*)d_in[8];
  const float* db     = (const float*)d_in[9];
  const float* tw     = (const float*)d_in[10];
  const float* tb     = (const float*)d_in[11];
  const float* ow     = (const float*)d_in[12];
  const float* ob     = (const float*)d_in[13];
  const int*   fidx   = (const int*)d_in[14];
  float* out = (float*)d_out;
  u16* pun = (u16*)d_out;                        // slot-packed O (lo) + xn (hi)

  u16* wpk2 = (u16*)d_ws;                        // 196608 u16
  u16* ppk  = wpk2 + 196608;                     // 65536
  u16* opk  = ppk + 65536;                       // 196608
  u16* E    = opk + 196608;                      // 1572864
  u16* RKQ  = E + 1572864;                       // 1048576
  u16* Rv   = RKQ + 1048576;                     // 524288   (~7.2 MB total)

  k_f0<<<2464, 256, 0, stream>>>(x, nsc, nbi, pun, qkv_w, proj_w, ow, tw,
                                 temb, tb, dw, db, fidx, wpk2, ppk, opk, E);
  k_rgemm<<<192, 256, 0, stream>>>(E, opk, ob, RKQ, Rv);
  k_attn<<<4096, 256, 0, stream>>>(pun, wpk2, qkv_b, RKQ, Rv);
  k_proj<<<2048, 256, 0, stream>>>(pun, ppk, proj_b, out);
}